// Round 5
// baseline (372.627 us; speedup 1.0000x reference)
//
#include <hip/hip_runtime.h>
#include <hip/hip_bf16.h>

// Problem constants
#define M_ROWS  32768   // B*H*W
#define D_DIM   512     // C == latent dim
#define K_CODES 1024
#define HW      1024
#define IMG_STRIDE (D_DIM * HW)   // 524288

// d_out scratch: zh swizzled bf16 (32 MB) lives in the out_q region until the
// final gather overwrites it. idx region (last 128 KB of d_out) is real output.
// ws layout (bytes):
#define WH_OFF   0u          // 1 MB   swizzled cb-hi bf16
#define A_OFF    1048576u    // 128 KB A[i] (numpy-pairwise)
#define W_OFF    1179648u    // 4 KB   W[n]
#define PK_OFF   1183744u    // 128 KB packed candidates/flags
#define PART_OFF 1312768u    // 2.62 MB per-(row,bn) top3 partials
#define WL1_OFF  3934208u    // 128 KB worklist flag==1
#define WL2_OFF  4065280u    // 128 KB worklist flag==2
#define CNT_OFF  4196352u    // 8 B    counters

// 1-term bf16 error: pairwise sigma ~4.3e-5 -> 7.5 sigma = 3.2e-4, plus fp32
// reorder/grid window 1.22e-4 -> 4.4e-4; pad to 5e-4.
#define WINDOW 5.0e-4f

// ---- exact RNE fp32 ops the compiler can't contract/reassociate ----
__device__ __forceinline__ float fmul32(float a, float b) {
  float r; asm volatile("v_mul_f32 %0, %1, %2" : "=v"(r) : "v"(a), "v"(b)); return r;
}
__device__ __forceinline__ float fadd32(float a, float b) {
  float r; asm volatile("v_add_f32 %0, %1, %2" : "=v"(r) : "v"(a), "v"(b)); return r;
}
__device__ __forceinline__ float pair8(const float* r) {
  return fadd32(fadd32(fadd32(r[0], r[1]), fadd32(r[2], r[3])),
                fadd32(fadd32(r[4], r[5]), fadd32(r[6], r[7])));
}

__device__ __forceinline__ unsigned short f2bf(float x) {
  __hip_bfloat16 h = __float2bfloat16(x);
  unsigned short u; __builtin_memcpy(&u, &h, 2); return u;
}

typedef __attribute__((ext_vector_type(8))) short b8;
typedef __attribute__((ext_vector_type(4))) float f4;

// top-3 tracking (values s1<=s2<=s3; indices for first two; first-index ties)
struct T3 { float s1, s2, s3; int n1, n2; };
__device__ __forceinline__ void t3_merge(T3& a, const T3& bb) {
  T3 x = a, y = bb;
  bool bf = (y.s1 < x.s1) || (y.s1 == x.s1 && y.n1 < x.n1);
  if (bf) { T3 t = x; x = y; y = t; }
  float rs2; int rn2; float rs3;
  bool c2 = (y.s1 < x.s2) || (y.s1 == x.s2 && y.n1 < x.n2);
  if (c2) { rs2 = y.s1; rn2 = y.n1; rs3 = fminf(x.s2, y.s2); }
  else    { rs2 = x.s2; rn2 = x.n2; rs3 = fminf(x.s3, y.s1); }
  a.s1 = x.s1; a.n1 = x.n1; a.s2 = rs2; a.n2 = rn2; a.s3 = rs3;
}

// ---------------------------------------------------------------------------
// Fused: A[i] = np.sum(z^2) (exact numpy fp32 pairwise order, round-3 code
// path untouched) + zh swizzled-bf16 emission. One pass over z.
// zh layout: [kc 16][mb 2048][q 4][m15 16][j 8] bf16.
__global__ __launch_bounds__(256) void vq_prep(const float* __restrict__ z,
                                               float* __restrict__ A,
                                               char* __restrict__ zh_b) {
  __shared__ float zs[4][64 * 68];
  const int wave = threadIdx.x >> 6, t = threadIdx.x & 63;
  const int i0 = blockIdx.x * 256 + wave * 64;
  const int b = i0 >> 10, hw0 = i0 & 1023;
  const float* zbase = z + (size_t)b * IMG_STRIDE + hw0;
  float* zsw = zs[wave];
  const int pos = i0 + t;
  const size_t mbase = (size_t)(pos >> 4) * 1024 + (size_t)(pos & 15) * 16;
  float r8[8], blk[4];
  alignas(16) unsigned short hs[8];
#pragma unroll
  for (int ch = 0; ch < 8; ++ch) {
    __syncthreads();
    {
      const int l = t & 15, j0 = t >> 4;
#pragma unroll
      for (int jj = 0; jj < 16; ++jj) {
        int j = j0 * 16 + jj;
        float4 vv = *(const float4*)(zbase + (size_t)(ch * 64 + j) * HW + 4 * l);
        *(float4*)(zsw + j * 68 + 4 * l) = vv;
      }
    }
    __syncthreads();
#pragma unroll
    for (int j = 0; j < 64; ++j) {
      const int c = ch * 64 + j;
      float v = zsw[j * 68 + t];
      hs[j & 7] = f2bf(v);
      if ((j & 7) == 7) {
        const int kc = c >> 5, q = (c >> 3) & 3;
        *(uint4*)(zh_b + (size_t)kc * 2097152 + q * 256 + mbase) = *(uint4*)hs;
      }
      float pq = fmul32(v, v);
      const int k = c & 7, m = c & 127;
      if (m < 8) r8[k] = pq;
      else       r8[k] = fadd32(r8[k], pq);
      if (m == 127) blk[c >> 7] = pair8(r8);
    }
  }
  A[pos] = fadd32(fadd32(blk[0], blk[1]), fadd32(blk[2], blk[3]));
}

// Fused: W[n] = np.sum(cb^2) (exact pairwise order) + wh swizzled emission.
// wh layout: [kc 16][nb 64][q 4][n15 16][j 8] bf16. Also zeroes counters.
__global__ void vq_prepw(const float* __restrict__ cb, float* __restrict__ W,
                         char* __restrict__ wh_b, int* __restrict__ cnt) {
  if (blockIdx.x == 0 && threadIdx.x < 2) cnt[threadIdx.x] = 0;
  const int n = blockIdx.x * 256 + threadIdx.x;
  const float* wp = cb + (size_t)n * D_DIM;
  const size_t nbase = (size_t)(n >> 4) * 1024 + (size_t)(n & 15) * 16;
  float r8[8], blk[4];
  alignas(16) unsigned short hs[8];
#pragma unroll
  for (int bb = 0; bb < 4; ++bb) {
#pragma unroll
    for (int g = 0; g < 16; ++g) {
      float vv[8];
#pragma unroll
      for (int k = 0; k < 8; ++k) vv[k] = wp[bb * 128 + g * 8 + k];
#pragma unroll
      for (int k = 0; k < 8; ++k) {
        float pq = fmul32(vv[k], vv[k]);
        if (g == 0) r8[k] = pq;
        else        r8[k] = fadd32(r8[k], pq);
        hs[k] = f2bf(vv[k]);
      }
      const int kc = bb * 4 + (g >> 2), q = g & 3;
      *(uint4*)(wh_b + (size_t)kc * 65536 + q * 256 + nbase) = *(uint4*)hs;
    }
    blk[bb] = pair8(r8);
  }
  W[n] = fadd32(fadd32(blk[0], blk[1]), fadd32(blk[2], blk[3]));
}

// ---------------------------------------------------------------------------
// 1-term MFMA scoring: M ~= zh·wh (bf16, fp32 acc); s = W - 2M.
// R4: SWAPPED OPERANDS — C = mfma(wh, zh): rows = n (codes), cols = m (pos).
// R3's counters (MfmaUtil 17, VALUBusy 34, 49% idle) showed the top-3
// epilogue dominated: reduction axis n was spread over 16 lanes -> 16
// instances x 4 butterfly steps x 5 shuffles = 320 shuffles/lane. With n as
// C-rows, each lane holds 32 n-scores of one m in-register: local top-3 is
// shuffle-free, then 2 butterfly steps merge the 4 quad groups (40 shuffles).
// Same products, same per-element MFMA k-tree, same kc order -> bit-equal.
// Block tile: 256 n x 128 m; wave = (n-half, m-half): 128 n x 64 m,
// acc[8 n-tiles][4 m-tiles].
__global__ __launch_bounds__(256, 2) void vq_score(
    const char* __restrict__ zh_b, const char* __restrict__ wh_b,
    const float* __restrict__ Wws, float* __restrict__ part)
{
  __shared__ float red[1280];   // [128 m][2 n-half][5] epilogue reduce
  const int tid = threadIdx.x;
  const int lane = tid & 63, wave = tid >> 6;
  const int wnh = wave >> 1, wm = wave & 1;   // n-half, m-half
  const int bm = blockIdx.x & 255, bn = blockIdx.x >> 8;
  const int m0 = bm * 128, n0 = bn * 256;

  f4 acc[8][4];
#pragma unroll
  for (int nt = 0; nt < 8; ++nt)
#pragma unroll
    for (int v = 0; v < 4; ++v) acc[nt][v] = (f4)(0.0f);

  // Fragment addresses (bases wave-uniform -> SGPR; per-lane only lane*16):
  // wh seg (wnh*8+nt) of block's 16KB/kc; zh seg (wm*4+v) of block's 8KB/kc.
  const size_t laneoff = (size_t)lane * 16;
  const char* gWbase = wh_b + (size_t)bn * 16384 + (size_t)wnh * 8192;
  const char* gZbase = zh_b + (size_t)bm * 8192  + (size_t)wm  * 4096;

  b8 aw[2][8], bz[2][4];
#pragma unroll
  for (int nt = 0; nt < 8; ++nt)
    aw[0][nt] = *(const b8*)(gWbase + nt * 1024 + laneoff);
#pragma unroll
  for (int v = 0; v < 4; ++v)
    bz[0][v] = *(const b8*)(gZbase + v * 1024 + laneoff);

#pragma unroll
  for (int kc = 0; kc < 16; ++kc) {
    const int cur = kc & 1, nxt = cur ^ 1;
    if (kc + 1 < 16) {
      const char* gW = gWbase + (size_t)(kc + 1) * 65536;
      const char* gZ = gZbase + (size_t)(kc + 1) * 2097152;
#pragma unroll
      for (int nt = 0; nt < 8; ++nt) aw[nxt][nt] = *(const b8*)(gW + nt * 1024 + laneoff);
#pragma unroll
      for (int v = 0; v < 4; ++v)    bz[nxt][v]  = *(const b8*)(gZ + v * 1024 + laneoff);
    }
#pragma unroll
    for (int nt = 0; nt < 8; ++nt) {
#pragma unroll
      for (int v = 0; v < 4; ++v)
        acc[nt][v] = __builtin_amdgcn_mfma_f32_16x16x32_bf16(aw[cur][nt], bz[cur][v],
                                                             acc[nt][v], 0, 0, 0);
    }
  }

  // epilogue: s = W - 2M; lane holds n = nb + nt*16 + q*4 + reg (32 values)
  // for m = m0 + wm*64 + v*16 + l15.
  const int l15 = lane & 15, q = lane >> 4;
  const int nb = n0 + wnh * 128 + q * 4;

  float4 w4[8];
#pragma unroll
  for (int nt = 0; nt < 8; ++nt)
    w4[nt] = *(const float4*)(Wws + nb + nt * 16);

#pragma unroll
  for (int v = 0; v < 4; ++v) {
    T3 t; t.s1 = t.s2 = t.s3 = 3.4e38f; t.n1 = 0; t.n2 = 0;
#pragma unroll
    for (int nt = 0; nt < 8; ++nt) {
      const float* wv = (const float*)&w4[nt];
#pragma unroll
      for (int reg = 0; reg < 4; ++reg) {     // n strictly increasing in scan
        float s = fmaf(-2.f, acc[nt][v][reg], wv[reg]);
        int n = nb + nt * 16 + reg;
        bool c1 = s < t.s1, c2 = s < t.s2;
        float ns3 = fminf(t.s3, fmaxf(t.s2, s));   // 3rd of {s1,s2,s3,s}
        float ns2 = __builtin_amdgcn_fmed3f(t.s1, t.s2, s);  // 2nd of {s1,s2,s}
        t.n2 = c1 ? t.n1 : (c2 ? n : t.n2);
        t.n1 = c1 ? n : t.n1;
        t.s1 = fminf(t.s1, s);
        t.s2 = ns2; t.s3 = ns3;
      }
    }
#pragma unroll
    for (int m = 16; m <= 32; m <<= 1) {   // merge the 4 quad groups
      T3 o;
      o.s1 = __shfl_xor(t.s1, m); o.s2 = __shfl_xor(t.s2, m); o.s3 = __shfl_xor(t.s3, m);
      o.n1 = __shfl_xor(t.n1, m); o.n2 = __shfl_xor(t.n2, m);
      t3_merge(t, o);
    }
    if (q == 0) {
      int row = wm * 64 + v * 16 + l15;
      float* d = red + (row * 2 + wnh) * 5;
      d[0] = t.s1; d[1] = t.s2; d[2] = t.s3; d[3] = (float)t.n1; d[4] = (float)t.n2;
    }
  }
  __syncthreads();
  if (tid < 128) {
    const float* d0 = red + (tid * 2) * 5;
    const float* d1 = red + (tid * 2 + 1) * 5;
    T3 a; a.s1 = d0[0]; a.s2 = d0[1]; a.s3 = d0[2]; a.n1 = (int)d0[3]; a.n2 = (int)d0[4];
    T3 b; b.s1 = d1[0]; b.s2 = d1[1]; b.s3 = d1[2]; b.n1 = (int)d1[3]; b.n2 = (int)d1[4];
    t3_merge(a, b);
    float* p = part + ((size_t)(m0 + tid) * 4 + bn) * 5;
    p[0] = a.s1; p[1] = a.s2; p[2] = a.s3; p[3] = (float)a.n1; p[4] = (float)a.n2;
  }
}

// Combine 4 n-slices per row; write idx, packed candidates, and worklists.
__global__ void vq_comb(const float* __restrict__ part, float* __restrict__ out_idx,
                        unsigned int* __restrict__ pk, int* __restrict__ wl1,
                        int* __restrict__ wl2, int* __restrict__ cnt) {
  int row = blockIdx.x * 256 + threadIdx.x;
  const float* p = part + (size_t)row * 20;
  T3 a; a.s1 = p[0]; a.s2 = p[1]; a.s3 = p[2]; a.n1 = (int)p[3]; a.n2 = (int)p[4];
#pragma unroll
  for (int j = 1; j < 4; ++j) {
    const float* q = p + j * 5;
    T3 b; b.s1 = q[0]; b.s2 = q[1]; b.s3 = q[2]; b.n1 = (int)q[3]; b.n2 = (int)q[4];
    t3_merge(a, b);
  }
  out_idx[row] = (float)a.n1;
  unsigned int f = 0;
  if (a.s2 - a.s1 < WINDOW) f = (a.s3 - a.s1 < WINDOW) ? 2u : 1u;
  pk[row] = (unsigned int)a.n1 | ((unsigned int)a.n2 << 10) | (f << 20);
  if (f == 1u) wl1[atomicAdd(&cnt[0], 1)] = row;
  if (f == 2u) wl2[atomicAdd(&cnt[1], 1)] = row;
}

// fp64 top-2 recheck with reference-exact final combine; one wave per row.
__global__ __launch_bounds__(256) void vq_recheckA(
    const float* __restrict__ z, const float* __restrict__ cb,
    const float* __restrict__ Aws, const float* __restrict__ Wws,
    const unsigned int* __restrict__ pk, const int* __restrict__ wl1,
    const int* __restrict__ cnt, float* __restrict__ out_idx)
{
  const int wave = threadIdx.x >> 6, lane = threadIdx.x & 63;
  const int gw = blockIdx.x * 4 + wave;
  const int c1 = cnt[0];
  for (int i = gw; i < c1; i += 2048) {
    int row = wl1[i];
    unsigned int p = pk[row];
    int n1 = p & 1023, n2 = (p >> 10) & 1023;
    int b = row >> 10, hw = row & 1023;
    const float* zr = z + (size_t)b * IMG_STRIDE + hw;
    const float* c1p = cb + (size_t)n1 * D_DIM;
    const float* c2p = cb + (size_t)n2 * D_DIM;
    double d1 = 0.0, d2 = 0.0;
#pragma unroll
    for (int j = 0; j < 8; ++j) {
      int c = lane + 64 * j;
      double zv = (double)zr[(size_t)c * HW];
      d1 += zv * (double)c1p[c];
      d2 += zv * (double)c2p[c];
    }
#pragma unroll
    for (int off = 32; off > 0; off >>= 1) {
      d1 += __shfl_down(d1, off);
      d2 += __shfl_down(d2, off);
    }
    if (lane == 0) {
      float A_ = Aws[row];
      float e1 = fadd32(fadd32(A_, -2.f * (float)d1), Wws[n1]);
      float e2 = fadd32(fadd32(A_, -2.f * (float)d2), Wws[n2]);
      int win = (e2 < e1 || (e2 == e1 && n2 < n1)) ? n2 : n1;
      out_idx[row] = (float)win;
    }
  }
}

// Full 1024-code fp64 rescan for flag==2 rows.
// R1 rewrite: 512 blocks (1 row/block typical), float4 cb loads, 4 independent
// fp64 accumulators. fp64 reassoc error ~5e-16 << fp32 ulp (~1e-9) of the
// scores, so the (float)dot rounding and all tie rules are unaffected.
__global__ __launch_bounds__(256) void vq_recheckB(
    const float* __restrict__ z, const float* __restrict__ cb,
    const float* __restrict__ Aws, const float* __restrict__ Wws,
    const int* __restrict__ wl2, const int* __restrict__ cnt,
    float* __restrict__ out_idx)
{
  __shared__ double zd[512];
  __shared__ float rd[256];
  __shared__ int rn[256];
  const int c2 = cnt[1];
  for (int t = blockIdx.x; t < c2; t += gridDim.x) {
    int row = wl2[t];
    int b = row >> 10, hw = row & 1023;
    const float* zr = z + (size_t)b * IMG_STRIDE + hw;
    for (int c = threadIdx.x; c < 512; c += 256) zd[c] = (double)zr[(size_t)c * HW];
    __syncthreads();
    float best = 3.4e38f; int bn_ = 0;
    float A_ = Aws[row];
    for (int k = 0; k < 4; ++k) {
      int n = k * 256 + threadIdx.x;
      const float* cn = cb + (size_t)n * D_DIM;
      double a0 = 0.0, a1 = 0.0, a2 = 0.0, a3 = 0.0;
#pragma unroll 8
      for (int c4 = 0; c4 < 128; ++c4) {
        float4 w4 = *(const float4*)(cn + 4 * c4);
        a0 += zd[4 * c4 + 0] * (double)w4.x;   // zd reads are broadcast (all
        a1 += zd[4 * c4 + 1] * (double)w4.y;   // lanes same addr) — no bank
        a2 += zd[4 * c4 + 2] * (double)w4.z;   // conflicts.
        a3 += zd[4 * c4 + 3] * (double)w4.w;
      }
      double dot = (a0 + a1) + (a2 + a3);
      float e = fadd32(fadd32(A_, -2.f * (float)dot), Wws[n]);
      if (e < best || (e == best && n < bn_)) { best = e; bn_ = n; }
    }
    rd[threadIdx.x] = best; rn[threadIdx.x] = bn_;
    __syncthreads();
    for (int s = 128; s > 0; s >>= 1) {
      if (threadIdx.x < s) {
        float eo = rd[threadIdx.x + s]; int no = rn[threadIdx.x + s];
        if (eo < rd[threadIdx.x] || (eo == rd[threadIdx.x] && no < rn[threadIdx.x])) {
          rd[threadIdx.x] = eo; rn[threadIdx.x] = no;
        }
      }
      __syncthreads();
    }
    if (threadIdx.x == 0) out_idx[row] = (float)rn[0];
    __syncthreads();
  }
}

// Final gather: out_q rows = codebook rows (contiguous; no inverse permute).
// Runs last — overwrites the zh scratch living in the out_q region.
__global__ __launch_bounds__(256) void vq_gather(const float* __restrict__ cb,
                                                 const float* __restrict__ out_idx,
                                                 float* __restrict__ out_q) {
  __shared__ int bidx[64];
  const int i0 = blockIdx.x * 64;
  if (threadIdx.x < 64) bidx[threadIdx.x] = (int)out_idx[i0 + threadIdx.x];
  __syncthreads();
  float* outp = out_q + (size_t)i0 * D_DIM;
  for (int j = 0; j < 32; ++j) {
    int f4i = j * 256 + threadIdx.x;
    int row = f4i >> 7, d4 = f4i & 127;
    float4 vv = *(const float4*)(cb + (size_t)bidx[row] * D_DIM + 4 * d4);
    *(float4*)(outp + 4 * f4i) = vv;
  }
}

extern "C" void kernel_launch(void* const* d_in, const int* in_sizes, int n_in,
                              void* d_out, int out_size, void* d_ws, size_t ws_size,
                              hipStream_t stream) {
  const float* z  = (const float*)d_in[0];
  const float* cb = (const float*)d_in[1];
  float* out_q   = (float*)d_out;
  float* out_idx = (float*)d_out + (size_t)M_ROWS * D_DIM;
  char* zh_b = (char*)d_out;                // out_q region doubles as zh scratch
  char* ws = (char*)d_ws;
  char* wh_b = ws + WH_OFF;
  float* Aws = (float*)(ws + A_OFF);
  float* Wws = (float*)(ws + W_OFF);
  unsigned int* pk = (unsigned int*)(ws + PK_OFF);
  float* part = (float*)(ws + PART_OFF);
  int* wl1 = (int*)(ws + WL1_OFF);
  int* wl2 = (int*)(ws + WL2_OFF);
  int* cnt = (int*)(ws + CNT_OFF);

  vq_prep    <<<128, 256, 0, stream>>>(z, Aws, zh_b);
  vq_prepw   <<<4, 256, 0, stream>>>(cb, Wws, wh_b, cnt);
  vq_score   <<<1024, 256, 0, stream>>>(zh_b, wh_b, Wws, part);
  vq_comb    <<<128, 256, 0, stream>>>(part, out_idx, pk, wl1, wl2, cnt);
  vq_recheckA<<<512, 256, 0, stream>>>(z, cb, Aws, Wws, pk, wl1, cnt, out_idx);
  vq_recheckB<<<512, 256, 0, stream>>>(z, cb, Aws, Wws, wl2, cnt, out_idx);
  vq_gather  <<<512, 256, 0, stream>>>(cb, out_idx, out_q);
}

// Round 6
// 351.096 us; speedup vs baseline: 1.0613x; 1.0613x over previous
//
#include <hip/hip_runtime.h>
#include <hip/hip_bf16.h>

// Problem constants
#define M_ROWS  32768   // B*H*W
#define D_DIM   512     // C == latent dim
#define K_CODES 1024
#define HW      1024
#define IMG_STRIDE (D_DIM * HW)   // 524288

// d_out scratch: zh swizzled bf16 (32 MB) lives in the out_q region until the
// final gather overwrites it. idx region (last 128 KB of d_out) is real output.
// ws layout (bytes):
#define WH_OFF   0u          // 1 MB   swizzled cb-hi bf16
#define A_OFF    1048576u    // 128 KB A[i] (numpy-pairwise)
#define W_OFF    1179648u    // 4 KB   W[n]
#define PK_OFF   1183744u    // 128 KB packed candidates/flags
#define PART_OFF 1312768u    // 2.62 MB per-(row,bn) top3 partials
#define WL1_OFF  3934208u    // 128 KB worklist flag==1 (unused by A now)
#define WL2_OFF  4065280u    // 128 KB worklist flag==2
#define CNT_OFF  4196352u    // 8 B    counters

// 1-term bf16 error: pairwise sigma ~4.3e-5 -> 7.5 sigma = 3.2e-4, plus fp32
// reorder/grid window 1.22e-4 -> 4.4e-4; pad to 5e-4.
#define WINDOW 5.0e-4f

// ---- exact RNE fp32 ops the compiler can't contract/reassociate ----
__device__ __forceinline__ float fmul32(float a, float b) {
  float r; asm volatile("v_mul_f32 %0, %1, %2" : "=v"(r) : "v"(a), "v"(b)); return r;
}
__device__ __forceinline__ float fadd32(float a, float b) {
  float r; asm volatile("v_add_f32 %0, %1, %2" : "=v"(r) : "v"(a), "v"(b)); return r;
}
__device__ __forceinline__ float pair8(const float* r) {
  return fadd32(fadd32(fadd32(r[0], r[1]), fadd32(r[2], r[3])),
                fadd32(fadd32(r[4], r[5]), fadd32(r[6], r[7])));
}

__device__ __forceinline__ unsigned short f2bf(float x) {
  __hip_bfloat16 h = __float2bfloat16(x);
  unsigned short u; __builtin_memcpy(&u, &h, 2); return u;
}

typedef __attribute__((ext_vector_type(8))) short b8;
typedef __attribute__((ext_vector_type(4))) float f4;

// top-3 tracking (values s1<=s2<=s3; indices for first two; first-index ties)
struct T3 { float s1, s2, s3; int n1, n2; };
__device__ __forceinline__ void t3_merge(T3& a, const T3& bb) {
  T3 x = a, y = bb;
  bool bf = (y.s1 < x.s1) || (y.s1 == x.s1 && y.n1 < x.n1);
  if (bf) { T3 t = x; x = y; y = t; }
  float rs2; int rn2; float rs3;
  bool c2 = (y.s1 < x.s2) || (y.s1 == x.s2 && y.n1 < x.n2);
  if (c2) { rs2 = y.s1; rn2 = y.n1; rs3 = fminf(x.s2, y.s2); }
  else    { rs2 = x.s2; rn2 = x.n2; rs3 = fminf(x.s3, y.s1); }
  a.s1 = x.s1; a.n1 = x.n1; a.s2 = rs2; a.n2 = rn2; a.s3 = rs3;
}

// ---------------------------------------------------------------------------
// Fused: A[i] = np.sum(z^2) (exact numpy fp32 pairwise order) + zh swizzled
// bf16 emission. One pass over z. zh: [kc 16][mb 2048][q 4][m15 16][j 8] bf16.
// R5: 256 blocks x 128 threads (was 128 x 256 — half the CUs sat idle).
// Per-thread code identical; only the block geometry changed.
__global__ __launch_bounds__(128) void vq_prep(const float* __restrict__ z,
                                               float* __restrict__ A,
                                               char* __restrict__ zh_b) {
  __shared__ float zs[2][64 * 68];
  const int wave = threadIdx.x >> 6, t = threadIdx.x & 63;
  const int i0 = blockIdx.x * 128 + wave * 64;
  const int b = i0 >> 10, hw0 = i0 & 1023;
  const float* zbase = z + (size_t)b * IMG_STRIDE + hw0;
  float* zsw = zs[wave];
  const int pos = i0 + t;
  const size_t mbase = (size_t)(pos >> 4) * 1024 + (size_t)(pos & 15) * 16;
  float r8[8], blk[4];
  alignas(16) unsigned short hs[8];
#pragma unroll
  for (int ch = 0; ch < 8; ++ch) {
    __syncthreads();
    {
      const int l = t & 15, j0 = t >> 4;
#pragma unroll
      for (int jj = 0; jj < 16; ++jj) {
        int j = j0 * 16 + jj;
        float4 vv = *(const float4*)(zbase + (size_t)(ch * 64 + j) * HW + 4 * l);
        *(float4*)(zsw + j * 68 + 4 * l) = vv;
      }
    }
    __syncthreads();
#pragma unroll
    for (int j = 0; j < 64; ++j) {
      const int c = ch * 64 + j;
      float v = zsw[j * 68 + t];
      hs[j & 7] = f2bf(v);
      if ((j & 7) == 7) {
        const int kc = c >> 5, q = (c >> 3) & 3;
        *(uint4*)(zh_b + (size_t)kc * 2097152 + q * 256 + mbase) = *(uint4*)hs;
      }
      float pq = fmul32(v, v);
      const int k = c & 7, m = c & 127;
      if (m < 8) r8[k] = pq;
      else       r8[k] = fadd32(r8[k], pq);
      if (m == 127) blk[c >> 7] = pair8(r8);
    }
  }
  A[pos] = fadd32(fadd32(blk[0], blk[1]), fadd32(blk[2], blk[3]));
}

// Fused: W[n] = np.sum(cb^2) (exact pairwise order) + wh swizzled emission.
// wh layout: [kc 16][nb 64][q 4][n15 16][j 8] bf16. Also zeroes counters.
__global__ void vq_prepw(const float* __restrict__ cb, float* __restrict__ W,
                         char* __restrict__ wh_b, int* __restrict__ cnt) {
  if (blockIdx.x == 0 && threadIdx.x < 2) cnt[threadIdx.x] = 0;
  const int n = blockIdx.x * 256 + threadIdx.x;
  const float* wp = cb + (size_t)n * D_DIM;
  const size_t nbase = (size_t)(n >> 4) * 1024 + (size_t)(n & 15) * 16;
  float r8[8], blk[4];
  alignas(16) unsigned short hs[8];
#pragma unroll
  for (int bb = 0; bb < 4; ++bb) {
#pragma unroll
    for (int g = 0; g < 16; ++g) {
      float vv[8];
#pragma unroll
      for (int k = 0; k < 8; ++k) vv[k] = wp[bb * 128 + g * 8 + k];
#pragma unroll
      for (int k = 0; k < 8; ++k) {
        float pq = fmul32(vv[k], vv[k]);
        if (g == 0) r8[k] = pq;
        else        r8[k] = fadd32(r8[k], pq);
        hs[k] = f2bf(vv[k]);
      }
      const int kc = bb * 4 + (g >> 2), q = g & 3;
      *(uint4*)(wh_b + (size_t)kc * 65536 + q * 256 + nbase) = *(uint4*)hs;
    }
    blk[bb] = pair8(r8);
  }
  W[n] = fadd32(fadd32(blk[0], blk[1]), fadd32(blk[2], blk[3]));
}

// ---------------------------------------------------------------------------
// 1-term MFMA scoring: M ~= zh·wh (bf16, fp32 acc); s = W - 2M.
// R5: reverted to the verified R3 version (80.6 µs). R4's operand swap cut
// epilogue VALU as predicted (34->12%) but doubled idle time (mechanism not
// identified from counters) -> net regression; per post-mortem rules the
// unexplained change is reverted.
__global__ __launch_bounds__(256, 2) void vq_score(
    const char* __restrict__ zh_b, const char* __restrict__ wh_b,
    const float* __restrict__ Wws, float* __restrict__ part)
{
  __shared__ float red[1280];   // [128 rows][2 wc][5] epilogue reduce
  const int tid = threadIdx.x;
  const int lane = tid & 63, wave = tid >> 6;
  const int wr = wave >> 1, wc = wave & 1;
  const int bm = blockIdx.x & 255, bn = blockIdx.x >> 8;
  const int m0 = bm * 128, n0 = bn * 256;

  f4 acc[4][8];
#pragma unroll
  for (int r = 0; r < 4; ++r)
#pragma unroll
    for (int v = 0; v < 8; ++v) acc[r][v] = (f4)(0.0f);

  // per-wave fragment base pointers (identical bytes to the old LDS path):
  // ah(r,kc) = zh[kc*2M + bm*8192 + (wr*4+r)*1024 + lane*16 ..+16)
  // bh(v,kc) = wh[kc*64K + bn*16384 + (wc*8+v)*1024 + lane*16 ..+16)
  const char* gA_w = zh_b + (size_t)bm * 8192 + (size_t)(wr * 4) * 1024 + (size_t)lane * 16;
  const char* gB_w = wh_b + (size_t)bn * 16384 + (size_t)(wc * 8) * 1024 + (size_t)lane * 16;

  b8 ar[2][4], br[2][8];
#pragma unroll
  for (int r = 0; r < 4; ++r)
    ar[0][r] = *(const b8*)(gA_w + (size_t)r * 1024);
#pragma unroll
  for (int v = 0; v < 8; ++v)
    br[0][v] = *(const b8*)(gB_w + (size_t)v * 1024);

#pragma unroll
  for (int kc = 0; kc < 16; ++kc) {
    const int cur = kc & 1, nxt = cur ^ 1;
    if (kc + 1 < 16) {
      const char* gA = gA_w + (size_t)(kc + 1) * 2097152;
      const char* gB = gB_w + (size_t)(kc + 1) * 65536;
#pragma unroll
      for (int r = 0; r < 4; ++r) ar[nxt][r] = *(const b8*)(gA + (size_t)r * 1024);
#pragma unroll
      for (int v = 0; v < 8; ++v) br[nxt][v] = *(const b8*)(gB + (size_t)v * 1024);
    }
#pragma unroll
    for (int r = 0; r < 4; ++r) {
#pragma unroll
      for (int v = 0; v < 8; ++v)
        acc[r][v] = __builtin_amdgcn_mfma_f32_16x16x32_bf16(ar[cur][r], br[cur][v],
                                                            acc[r][v], 0, 0, 0);
    }
  }

  // epilogue: s = W - 2M; per-row top-3 across this block's 256 n
  const int l15 = lane & 15, quad = lane >> 4;
  float sW[8];
#pragma unroll
  for (int v = 0; v < 8; ++v) sW[v] = Wws[n0 + wc * 128 + v * 16 + l15];

#pragma unroll
  for (int r = 0; r < 4; ++r) {
#pragma unroll
    for (int reg = 0; reg < 4; ++reg) {
      T3 t; t.s1 = t.s2 = t.s3 = 3.4e38f; t.n1 = 0; t.n2 = 0;
#pragma unroll
      for (int v = 0; v < 8; ++v) {
        float s = fmaf(-2.f, acc[r][v][reg], sW[v]);
        int n = n0 + wc * 128 + v * 16 + l15;
        if (s < t.s1)      { t.s3 = t.s2; t.s2 = t.s1; t.n2 = t.n1; t.s1 = s; t.n1 = n; }
        else if (s < t.s2) { t.s3 = t.s2; t.s2 = s; t.n2 = n; }
        else if (s < t.s3) { t.s3 = s; }
      }
#pragma unroll
      for (int m = 1; m <= 8; m <<= 1) {   // butterfly within 16-lane quad
        T3 o;
        o.s1 = __shfl_xor(t.s1, m); o.s2 = __shfl_xor(t.s2, m); o.s3 = __shfl_xor(t.s3, m);
        o.n1 = __shfl_xor(t.n1, m); o.n2 = __shfl_xor(t.n2, m);
        t3_merge(t, o);
      }
      if (l15 == 0) {
        int row = wr * 64 + r * 16 + quad * 4 + reg;
        float* d = red + (row * 2 + wc) * 5;
        d[0] = t.s1; d[1] = t.s2; d[2] = t.s3; d[3] = (float)t.n1; d[4] = (float)t.n2;
      }
    }
  }
  __syncthreads();
  if (tid < 128) {
    const float* d0 = red + (tid * 2) * 5;
    const float* d1 = red + (tid * 2 + 1) * 5;
    T3 a; a.s1 = d0[0]; a.s2 = d0[1]; a.s3 = d0[2]; a.n1 = (int)d0[3]; a.n2 = (int)d0[4];
    T3 b; b.s1 = d1[0]; b.s2 = d1[1]; b.s3 = d1[2]; b.n1 = (int)d1[3]; b.n2 = (int)d1[4];
    t3_merge(a, b);
    float* p = part + ((size_t)(m0 + tid) * 4 + bn) * 5;
    p[0] = a.s1; p[1] = a.s2; p[2] = a.s3; p[3] = (float)a.n1; p[4] = (float)a.n2;
  }
}

// Combine 4 n-slices per row; write idx, packed candidates, and worklists.
__global__ void vq_comb(const float* __restrict__ part, float* __restrict__ out_idx,
                        unsigned int* __restrict__ pk, int* __restrict__ wl1,
                        int* __restrict__ wl2, int* __restrict__ cnt) {
  int row = blockIdx.x * 256 + threadIdx.x;
  const float* p = part + (size_t)row * 20;
  T3 a; a.s1 = p[0]; a.s2 = p[1]; a.s3 = p[2]; a.n1 = (int)p[3]; a.n2 = (int)p[4];
#pragma unroll
  for (int j = 1; j < 4; ++j) {
    const float* q = p + j * 5;
    T3 b; b.s1 = q[0]; b.s2 = q[1]; b.s3 = q[2]; b.n1 = (int)q[3]; b.n2 = (int)q[4];
    t3_merge(a, b);
  }
  out_idx[row] = (float)a.n1;
  unsigned int f = 0;
  if (a.s2 - a.s1 < WINDOW) f = (a.s3 - a.s1 < WINDOW) ? 2u : 1u;
  pk[row] = (unsigned int)a.n1 | ((unsigned int)a.n2 << 10) | (f << 20);
  if (f == 1u) wl1[atomicAdd(&cnt[0], 1)] = row;
  if (f == 2u) wl2[atomicAdd(&cnt[1], 1)] = row;
}

// fp64 top-2 recheck with reference-exact final combine; one wave per row.
// R5: direct row mapping (wave i -> row i, 8192 blocks) instead of the
// atomic-append worklist. A z row read is 512 distinct 64B lines (stride
// 4 KB); worklist order scattered those reads. Now the 4 waves of a block
// handle 4 consecutive hw -> identical line set (L1 serves repeats), and
// neighboring blocks share via L2/L3. Per-row math untouched -> bit-equal.
__global__ __launch_bounds__(256) void vq_recheckA(
    const float* __restrict__ z, const float* __restrict__ cb,
    const float* __restrict__ Aws, const float* __restrict__ Wws,
    const unsigned int* __restrict__ pk, float* __restrict__ out_idx)
{
  const int wave = threadIdx.x >> 6, lane = threadIdx.x & 63;
  const int row = blockIdx.x * 4 + wave;
  unsigned int p = pk[row];
  if (((p >> 20) & 3u) != 1u) return;
  int n1 = p & 1023, n2 = (p >> 10) & 1023;
  int b = row >> 10, hw = row & 1023;
  const float* zr = z + (size_t)b * IMG_STRIDE + hw;
  const float* c1p = cb + (size_t)n1 * D_DIM;
  const float* c2p = cb + (size_t)n2 * D_DIM;
  double d1 = 0.0, d2 = 0.0;
#pragma unroll
  for (int j = 0; j < 8; ++j) {
    int c = lane + 64 * j;
    double zv = (double)zr[(size_t)c * HW];
    d1 += zv * (double)c1p[c];
    d2 += zv * (double)c2p[c];
  }
#pragma unroll
  for (int off = 32; off > 0; off >>= 1) {
    d1 += __shfl_down(d1, off);
    d2 += __shfl_down(d2, off);
  }
  if (lane == 0) {
    float A_ = Aws[row];
    float e1 = fadd32(fadd32(A_, -2.f * (float)d1), Wws[n1]);
    float e2 = fadd32(fadd32(A_, -2.f * (float)d2), Wws[n2]);
    int win = (e2 < e1 || (e2 == e1 && n2 < n1)) ? n2 : n1;
    out_idx[row] = (float)win;
  }
}

// Full 1024-code fp64 rescan for flag==2 rows (rare).
__global__ __launch_bounds__(256) void vq_recheckB(
    const float* __restrict__ z, const float* __restrict__ cb,
    const float* __restrict__ Aws, const float* __restrict__ Wws,
    const int* __restrict__ wl2, const int* __restrict__ cnt,
    float* __restrict__ out_idx)
{
  __shared__ double zd[512];
  __shared__ float rd[256];
  __shared__ int rn[256];
  const int c2 = cnt[1];
  for (int t = blockIdx.x; t < c2; t += gridDim.x) {
    int row = wl2[t];
    int b = row >> 10, hw = row & 1023;
    const float* zr = z + (size_t)b * IMG_STRIDE + hw;
    for (int c = threadIdx.x; c < 512; c += 256) zd[c] = (double)zr[(size_t)c * HW];
    __syncthreads();
    float best = 3.4e38f; int bn_ = 0;
    float A_ = Aws[row];
    for (int k = 0; k < 4; ++k) {
      int n = k * 256 + threadIdx.x;
      const float* cn = cb + (size_t)n * D_DIM;
      double a0 = 0.0, a1 = 0.0, a2 = 0.0, a3 = 0.0;
#pragma unroll 8
      for (int c4 = 0; c4 < 128; ++c4) {
        float4 w4 = *(const float4*)(cn + 4 * c4);
        a0 += zd[4 * c4 + 0] * (double)w4.x;
        a1 += zd[4 * c4 + 1] * (double)w4.y;
        a2 += zd[4 * c4 + 2] * (double)w4.z;
        a3 += zd[4 * c4 + 3] * (double)w4.w;
      }
      double dot = (a0 + a1) + (a2 + a3);
      float e = fadd32(fadd32(A_, -2.f * (float)dot), Wws[n]);
      if (e < best || (e == best && n < bn_)) { best = e; bn_ = n; }
    }
    rd[threadIdx.x] = best; rn[threadIdx.x] = bn_;
    __syncthreads();
    for (int s = 128; s > 0; s >>= 1) {
      if (threadIdx.x < s) {
        float eo = rd[threadIdx.x + s]; int no = rn[threadIdx.x + s];
        if (eo < rd[threadIdx.x] || (eo == rd[threadIdx.x] && no < rn[threadIdx.x])) {
          rd[threadIdx.x] = eo; rn[threadIdx.x] = no;
        }
      }
      __syncthreads();
    }
    if (threadIdx.x == 0) out_idx[row] = (float)rn[0];
    __syncthreads();
  }
}

// Final gather: out_q rows = codebook rows (contiguous; no inverse permute).
// R5: 2048 blocks x 16 rows (was 512 x 64) for more TLP on the 64 MB write.
__global__ __launch_bounds__(256) void vq_gather(const float* __restrict__ cb,
                                                 const float* __restrict__ out_idx,
                                                 float* __restrict__ out_q) {
  __shared__ int bidx[16];
  const int i0 = blockIdx.x * 16;
  if (threadIdx.x < 16) bidx[threadIdx.x] = (int)out_idx[i0 + threadIdx.x];
  __syncthreads();
  float* outp = out_q + (size_t)i0 * D_DIM;
#pragma unroll
  for (int j = 0; j < 8; ++j) {
    int f4i = j * 256 + threadIdx.x;
    int row = f4i >> 7, d4 = f4i & 127;
    float4 vv = *(const float4*)(cb + (size_t)bidx[row] * D_DIM + 4 * d4);
    *(float4*)(outp + 4 * f4i) = vv;
  }
}

extern "C" void kernel_launch(void* const* d_in, const int* in_sizes, int n_in,
                              void* d_out, int out_size, void* d_ws, size_t ws_size,
                              hipStream_t stream) {
  const float* z  = (const float*)d_in[0];
  const float* cb = (const float*)d_in[1];
  float* out_q   = (float*)d_out;
  float* out_idx = (float*)d_out + (size_t)M_ROWS * D_DIM;
  char* zh_b = (char*)d_out;                // out_q region doubles as zh scratch
  char* ws = (char*)d_ws;
  char* wh_b = ws + WH_OFF;
  float* Aws = (float*)(ws + A_OFF);
  float* Wws = (float*)(ws + W_OFF);
  unsigned int* pk = (unsigned int*)(ws + PK_OFF);
  float* part = (float*)(ws + PART_OFF);
  int* wl1 = (int*)(ws + WL1_OFF);
  int* wl2 = (int*)(ws + WL2_OFF);
  int* cnt = (int*)(ws + CNT_OFF);

  vq_prep    <<<256, 128, 0, stream>>>(z, Aws, zh_b);
  vq_prepw   <<<4, 256, 0, stream>>>(cb, Wws, wh_b, cnt);
  vq_score   <<<1024, 256, 0, stream>>>(zh_b, wh_b, Wws, part);
  vq_comb    <<<128, 256, 0, stream>>>(part, out_idx, pk, wl1, wl2, cnt);
  vq_recheckA<<<8192, 256, 0, stream>>>(z, cb, Aws, Wws, pk, out_idx);
  vq_recheckB<<<512, 256, 0, stream>>>(z, cb, Aws, Wws, wl2, cnt, out_idx);
  vq_gather  <<<2048, 256, 0, stream>>>(cb, out_idx, out_q);
}

// Round 7
// 298.946 us; speedup vs baseline: 1.2465x; 1.1744x over previous
//
#include <hip/hip_runtime.h>
#include <hip/hip_bf16.h>

// Problem constants
#define M_ROWS  32768   // B*H*W
#define D_DIM   512     // C == latent dim
#define K_CODES 1024
#define HW      1024
#define IMG_STRIDE (D_DIM * HW)   // 524288

// d_out scratch: zh swizzled bf16 (32 MB) lives in the out_q region until
// vq_final/vq_recheckB overwrite it (zh is dead after vq_score).
// ws layout (bytes):
#define WH_OFF   0u          // 1 MB   swizzled cb-hi bf16
#define A_OFF    1048576u    // 128 KB A[i] (numpy-pairwise)
#define W_OFF    1179648u    // 4 KB   W[n]
#define PK_OFF   1183744u    // 128 KB (unused since R6 fusion)
#define PART_OFF 1312768u    // 2.62 MB per-(row,bn) top3 partials
#define WL1_OFF  3934208u    // 128 KB (unused since R6 fusion)
#define WL2_OFF  4065280u    // 128 KB worklist flag==2
#define CNT_OFF  4196352u    // 8 B    counters

// 1-term bf16 error: pairwise sigma ~4.3e-5 -> 7.5 sigma = 3.2e-4, plus fp32
// reorder/grid window 1.22e-4 -> 4.4e-4; pad to 5e-4.
#define WINDOW 5.0e-4f

// ---- exact RNE fp32 ops the compiler can't contract/reassociate ----
__device__ __forceinline__ float fmul32(float a, float b) {
  float r; asm volatile("v_mul_f32 %0, %1, %2" : "=v"(r) : "v"(a), "v"(b)); return r;
}
__device__ __forceinline__ float fadd32(float a, float b) {
  float r; asm volatile("v_add_f32 %0, %1, %2" : "=v"(r) : "v"(a), "v"(b)); return r;
}
__device__ __forceinline__ float pair8(const float* r) {
  return fadd32(fadd32(fadd32(r[0], r[1]), fadd32(r[2], r[3])),
                fadd32(fadd32(r[4], r[5]), fadd32(r[6], r[7])));
}

__device__ __forceinline__ unsigned short f2bf(float x) {
  __hip_bfloat16 h = __float2bfloat16(x);
  unsigned short u; __builtin_memcpy(&u, &h, 2); return u;
}

typedef __attribute__((ext_vector_type(8))) short b8;
typedef __attribute__((ext_vector_type(4))) float f4;

// top-3 tracking (values s1<=s2<=s3; indices for first two; first-index ties)
struct T3 { float s1, s2, s3; int n1, n2; };
__device__ __forceinline__ void t3_merge(T3& a, const T3& bb) {
  T3 x = a, y = bb;
  bool bf = (y.s1 < x.s1) || (y.s1 == x.s1 && y.n1 < x.n1);
  if (bf) { T3 t = x; x = y; y = t; }
  float rs2; int rn2; float rs3;
  bool c2 = (y.s1 < x.s2) || (y.s1 == x.s2 && y.n1 < x.n2);
  if (c2) { rs2 = y.s1; rn2 = y.n1; rs3 = fminf(x.s2, y.s2); }
  else    { rs2 = x.s2; rn2 = x.n2; rs3 = fminf(x.s3, y.s1); }
  a.s1 = x.s1; a.n1 = x.n1; a.s2 = rs2; a.n2 = rn2; a.s3 = rs3;
}

// ---------------------------------------------------------------------------
// R6 FUSION: prep (blocks 0..255) + prepw (blocks 256..263) in one dispatch.
// Non-score time (~270 µs) is dominated by per-dispatch overhead, not kernel
// work — so the lever is fewer dispatches, not faster bodies. Bodies untouched.
// prep: A[i] = np.sum(z^2) exact pairwise + zh swizzled bf16 emission.
// prepw: W[n] = np.sum(cb^2) exact pairwise + wh emission + cnt zero.
__global__ __launch_bounds__(128) void vq_prep(const float* __restrict__ z,
                                               float* __restrict__ A,
                                               char* __restrict__ zh_b,
                                               const float* __restrict__ cb,
                                               float* __restrict__ W,
                                               char* __restrict__ wh_b,
                                               int* __restrict__ cnt) {
  __shared__ float zs[2][64 * 68];
  if (blockIdx.x >= 256) {      // ---- prepw part (8 blocks x 128 threads) ----
    if (blockIdx.x == 256 && threadIdx.x < 2) cnt[threadIdx.x] = 0;
    const int n = (blockIdx.x - 256) * 128 + threadIdx.x;
    const float* wp = cb + (size_t)n * D_DIM;
    const size_t nbase = (size_t)(n >> 4) * 1024 + (size_t)(n & 15) * 16;
    float r8w[8], blkw[4];
    alignas(16) unsigned short hsw[8];
#pragma unroll
    for (int bb = 0; bb < 4; ++bb) {
#pragma unroll
      for (int g = 0; g < 16; ++g) {
        float vv[8];
#pragma unroll
        for (int k = 0; k < 8; ++k) vv[k] = wp[bb * 128 + g * 8 + k];
#pragma unroll
        for (int k = 0; k < 8; ++k) {
          float pq = fmul32(vv[k], vv[k]);
          if (g == 0) r8w[k] = pq;
          else        r8w[k] = fadd32(r8w[k], pq);
          hsw[k] = f2bf(vv[k]);
        }
        const int kc = bb * 4 + (g >> 2), q = g & 3;
        *(uint4*)(wh_b + (size_t)kc * 65536 + q * 256 + nbase) = *(uint4*)hsw;
      }
      blkw[bb] = pair8(r8w);
    }
    W[n] = fadd32(fadd32(blkw[0], blkw[1]), fadd32(blkw[2], blkw[3]));
    return;
  }
  // ---- prep part (256 blocks x 128 threads) ----
  const int wave = threadIdx.x >> 6, t = threadIdx.x & 63;
  const int i0 = blockIdx.x * 128 + wave * 64;
  const int b = i0 >> 10, hw0 = i0 & 1023;
  const float* zbase = z + (size_t)b * IMG_STRIDE + hw0;
  float* zsw = zs[wave];
  const int pos = i0 + t;
  const size_t mbase = (size_t)(pos >> 4) * 1024 + (size_t)(pos & 15) * 16;
  float r8[8], blk[4];
  alignas(16) unsigned short hs[8];
#pragma unroll
  for (int ch = 0; ch < 8; ++ch) {
    __syncthreads();
    {
      const int l = t & 15, j0 = t >> 4;
#pragma unroll
      for (int jj = 0; jj < 16; ++jj) {
        int j = j0 * 16 + jj;
        float4 vv = *(const float4*)(zbase + (size_t)(ch * 64 + j) * HW + 4 * l);
        *(float4*)(zsw + j * 68 + 4 * l) = vv;
      }
    }
    __syncthreads();
#pragma unroll
    for (int j = 0; j < 64; ++j) {
      const int c = ch * 64 + j;
      float v = zsw[j * 68 + t];
      hs[j & 7] = f2bf(v);
      if ((j & 7) == 7) {
        const int kc = c >> 5, q = (c >> 3) & 3;
        *(uint4*)(zh_b + (size_t)kc * 2097152 + q * 256 + mbase) = *(uint4*)hs;
      }
      float pq = fmul32(v, v);
      const int k = c & 7, m = c & 127;
      if (m < 8) r8[k] = pq;
      else       r8[k] = fadd32(r8[k], pq);
      if (m == 127) blk[c >> 7] = pair8(r8);
    }
  }
  A[pos] = fadd32(fadd32(blk[0], blk[1]), fadd32(blk[2], blk[3]));
}

// ---------------------------------------------------------------------------
// 1-term MFMA scoring (R3 version, verified 80.6 µs — untouched).
__global__ __launch_bounds__(256, 2) void vq_score(
    const char* __restrict__ zh_b, const char* __restrict__ wh_b,
    const float* __restrict__ Wws, float* __restrict__ part)
{
  __shared__ float red[1280];   // [128 rows][2 wc][5] epilogue reduce
  const int tid = threadIdx.x;
  const int lane = tid & 63, wave = tid >> 6;
  const int wr = wave >> 1, wc = wave & 1;
  const int bm = blockIdx.x & 255, bn = blockIdx.x >> 8;
  const int m0 = bm * 128, n0 = bn * 256;

  f4 acc[4][8];
#pragma unroll
  for (int r = 0; r < 4; ++r)
#pragma unroll
    for (int v = 0; v < 8; ++v) acc[r][v] = (f4)(0.0f);

  const char* gA_w = zh_b + (size_t)bm * 8192 + (size_t)(wr * 4) * 1024 + (size_t)lane * 16;
  const char* gB_w = wh_b + (size_t)bn * 16384 + (size_t)(wc * 8) * 1024 + (size_t)lane * 16;

  b8 ar[2][4], br[2][8];
#pragma unroll
  for (int r = 0; r < 4; ++r)
    ar[0][r] = *(const b8*)(gA_w + (size_t)r * 1024);
#pragma unroll
  for (int v = 0; v < 8; ++v)
    br[0][v] = *(const b8*)(gB_w + (size_t)v * 1024);

#pragma unroll
  for (int kc = 0; kc < 16; ++kc) {
    const int cur = kc & 1, nxt = cur ^ 1;
    if (kc + 1 < 16) {
      const char* gA = gA_w + (size_t)(kc + 1) * 2097152;
      const char* gB = gB_w + (size_t)(kc + 1) * 65536;
#pragma unroll
      for (int r = 0; r < 4; ++r) ar[nxt][r] = *(const b8*)(gA + (size_t)r * 1024);
#pragma unroll
      for (int v = 0; v < 8; ++v) br[nxt][v] = *(const b8*)(gB + (size_t)v * 1024);
    }
#pragma unroll
    for (int r = 0; r < 4; ++r) {
#pragma unroll
      for (int v = 0; v < 8; ++v)
        acc[r][v] = __builtin_amdgcn_mfma_f32_16x16x32_bf16(ar[cur][r], br[cur][v],
                                                            acc[r][v], 0, 0, 0);
    }
  }

  const int l15 = lane & 15, quad = lane >> 4;
  float sW[8];
#pragma unroll
  for (int v = 0; v < 8; ++v) sW[v] = Wws[n0 + wc * 128 + v * 16 + l15];

#pragma unroll
  for (int r = 0; r < 4; ++r) {
#pragma unroll
    for (int reg = 0; reg < 4; ++reg) {
      T3 t; t.s1 = t.s2 = t.s3 = 3.4e38f; t.n1 = 0; t.n2 = 0;
#pragma unroll
      for (int v = 0; v < 8; ++v) {
        float s = fmaf(-2.f, acc[r][v][reg], sW[v]);
        int n = n0 + wc * 128 + v * 16 + l15;
        if (s < t.s1)      { t.s3 = t.s2; t.s2 = t.s1; t.n2 = t.n1; t.s1 = s; t.n1 = n; }
        else if (s < t.s2) { t.s3 = t.s2; t.s2 = s; t.n2 = n; }
        else if (s < t.s3) { t.s3 = s; }
      }
#pragma unroll
      for (int m = 1; m <= 8; m <<= 1) {   // butterfly within 16-lane quad
        T3 o;
        o.s1 = __shfl_xor(t.s1, m); o.s2 = __shfl_xor(t.s2, m); o.s3 = __shfl_xor(t.s3, m);
        o.n1 = __shfl_xor(t.n1, m); o.n2 = __shfl_xor(t.n2, m);
        t3_merge(t, o);
      }
      if (l15 == 0) {
        int row = wr * 64 + r * 16 + quad * 4 + reg;
        float* d = red + (row * 2 + wc) * 5;
        d[0] = t.s1; d[1] = t.s2; d[2] = t.s3; d[3] = (float)t.n1; d[4] = (float)t.n2;
      }
    }
  }
  __syncthreads();
  if (tid < 128) {
    const float* d0 = red + (tid * 2) * 5;
    const float* d1 = red + (tid * 2 + 1) * 5;
    T3 a; a.s1 = d0[0]; a.s2 = d0[1]; a.s3 = d0[2]; a.n1 = (int)d0[3]; a.n2 = (int)d0[4];
    T3 b; b.s1 = d1[0]; b.s2 = d1[1]; b.s3 = d1[2]; b.n1 = (int)d1[3]; b.n2 = (int)d1[4];
    t3_merge(a, b);
    float* p = part + ((size_t)(m0 + tid) * 4 + bn) * 5;
    p[0] = a.s1; p[1] = a.s2; p[2] = a.s3; p[3] = (float)a.n1; p[4] = (float)a.n2;
  }
}

// ---------------------------------------------------------------------------
// R6 FUSION: comb + recheckA + gather in one per-row-wave kernel.
// Wave -> row. Merge the 4 n-slice partials (identical t3 order), then:
//   flag 0: win = n1.                 flag 1: inline fp64 top-2 recheck.
//   flag 2: append to wl2 (recheckB finishes the row, incl. out_q).
// For flags 0/1 the wave also writes the 2 KB out_q row (was vq_gather) —
// zh scratch in the out_q region is dead after vq_score. Math identical.
__global__ __launch_bounds__(256) void vq_final(
    const float* __restrict__ part, const float* __restrict__ z,
    const float* __restrict__ cb, const float* __restrict__ Aws,
    const float* __restrict__ Wws, float* __restrict__ out_idx,
    float* __restrict__ out_q, int* __restrict__ wl2, int* __restrict__ cnt)
{
  const int wave = threadIdx.x >> 6, lane = threadIdx.x & 63;
  const int row = blockIdx.x * 4 + wave;
  const float* p = part + (size_t)row * 20;
  T3 a; a.s1 = p[0]; a.s2 = p[1]; a.s3 = p[2]; a.n1 = (int)p[3]; a.n2 = (int)p[4];
#pragma unroll
  for (int j = 1; j < 4; ++j) {
    const float* q = p + j * 5;
    T3 b; b.s1 = q[0]; b.s2 = q[1]; b.s3 = q[2]; b.n1 = (int)q[3]; b.n2 = (int)q[4];
    t3_merge(a, b);
  }
  unsigned int f = 0;
  if (a.s2 - a.s1 < WINDOW) f = (a.s3 - a.s1 < WINDOW) ? 2u : 1u;
  if (f == 2u) {                       // rare: full rescan handles everything
    if (lane == 0) wl2[atomicAdd(&cnt[1], 1)] = row;
    return;
  }
  int win = a.n1;
  if (f == 1u) {                       // fp64 top-2 recheck (math as before)
    int n1 = a.n1, n2 = a.n2;
    int b = row >> 10, hw = row & 1023;
    const float* zr = z + (size_t)b * IMG_STRIDE + hw;
    const float* c1p = cb + (size_t)n1 * D_DIM;
    const float* c2p = cb + (size_t)n2 * D_DIM;
    double d1 = 0.0, d2 = 0.0;
#pragma unroll
    for (int j = 0; j < 8; ++j) {
      int c = lane + 64 * j;
      double zv = (double)zr[(size_t)c * HW];
      d1 += zv * (double)c1p[c];
      d2 += zv * (double)c2p[c];
    }
#pragma unroll
    for (int off = 32; off > 0; off >>= 1) {
      d1 += __shfl_down(d1, off);
      d2 += __shfl_down(d2, off);
    }
    if (lane == 0) {
      float A_ = Aws[row];
      float e1 = fadd32(fadd32(A_, -2.f * (float)d1), Wws[n1]);
      float e2 = fadd32(fadd32(A_, -2.f * (float)d2), Wws[n2]);
      win = (e2 < e1 || (e2 == e1 && n2 < n1)) ? n2 : n1;
    }
    win = __shfl(win, 0);
  }
  if (lane == 0) out_idx[row] = (float)win;
  // gather: copy codebook row (L2-hot) to out_q — 64 lanes x 2 float4.
  const float4* src = (const float4*)(cb + (size_t)win * D_DIM);
  float4* dst = (float4*)(out_q + (size_t)row * D_DIM);
  dst[lane]      = src[lane];
  dst[lane + 64] = src[lane + 64];
}

// Full 1024-code fp64 rescan for flag==2 rows (rare); now also writes the
// out_q row (gather was deleted).
__global__ __launch_bounds__(256) void vq_recheckB(
    const float* __restrict__ z, const float* __restrict__ cb,
    const float* __restrict__ Aws, const float* __restrict__ Wws,
    const int* __restrict__ wl2, const int* __restrict__ cnt,
    float* __restrict__ out_idx, float* __restrict__ out_q)
{
  __shared__ double zd[512];
  __shared__ float rd[256];
  __shared__ int rn[256];
  const int c2 = cnt[1];
  for (int t = blockIdx.x; t < c2; t += gridDim.x) {
    int row = wl2[t];
    int b = row >> 10, hw = row & 1023;
    const float* zr = z + (size_t)b * IMG_STRIDE + hw;
    for (int c = threadIdx.x; c < 512; c += 256) zd[c] = (double)zr[(size_t)c * HW];
    __syncthreads();
    float best = 3.4e38f; int bn_ = 0;
    float A_ = Aws[row];
    for (int k = 0; k < 4; ++k) {
      int n = k * 256 + threadIdx.x;
      const float* cn = cb + (size_t)n * D_DIM;
      double a0 = 0.0, a1 = 0.0, a2 = 0.0, a3 = 0.0;
#pragma unroll 8
      for (int c4 = 0; c4 < 128; ++c4) {
        float4 w4 = *(const float4*)(cn + 4 * c4);
        a0 += zd[4 * c4 + 0] * (double)w4.x;
        a1 += zd[4 * c4 + 1] * (double)w4.y;
        a2 += zd[4 * c4 + 2] * (double)w4.z;
        a3 += zd[4 * c4 + 3] * (double)w4.w;
      }
      double dot = (a0 + a1) + (a2 + a3);
      float e = fadd32(fadd32(A_, -2.f * (float)dot), Wws[n]);
      if (e < best || (e == best && n < bn_)) { best = e; bn_ = n; }
    }
    rd[threadIdx.x] = best; rn[threadIdx.x] = bn_;
    __syncthreads();
    for (int s = 128; s > 0; s >>= 1) {
      if (threadIdx.x < s) {
        float eo = rd[threadIdx.x + s]; int no = rn[threadIdx.x + s];
        if (eo < rd[threadIdx.x] || (eo == rd[threadIdx.x] && no < rn[threadIdx.x])) {
          rd[threadIdx.x] = eo; rn[threadIdx.x] = no;
        }
      }
      __syncthreads();
    }
    int winb = rn[0];
    if (threadIdx.x == 0) out_idx[row] = (float)winb;
    {
      const float4* src = (const float4*)(cb + (size_t)winb * D_DIM);
      float4* dst = (float4*)(out_q + (size_t)row * D_DIM);
      if (threadIdx.x < 128) dst[threadIdx.x] = src[threadIdx.x];
    }
    __syncthreads();
  }
}

extern "C" void kernel_launch(void* const* d_in, const int* in_sizes, int n_in,
                              void* d_out, int out_size, void* d_ws, size_t ws_size,
                              hipStream_t stream) {
  const float* z  = (const float*)d_in[0];
  const float* cb = (const float*)d_in[1];
  float* out_q   = (float*)d_out;
  float* out_idx = (float*)d_out + (size_t)M_ROWS * D_DIM;
  char* zh_b = (char*)d_out;                // out_q region doubles as zh scratch
  char* ws = (char*)d_ws;
  char* wh_b = ws + WH_OFF;
  float* Aws = (float*)(ws + A_OFF);
  float* Wws = (float*)(ws + W_OFF);
  float* part = (float*)(ws + PART_OFF);
  int* wl2 = (int*)(ws + WL2_OFF);
  int* cnt = (int*)(ws + CNT_OFF);

  vq_prep    <<<264, 128, 0, stream>>>(z, Aws, zh_b, cb, Wws, wh_b, cnt);
  vq_score   <<<1024, 256, 0, stream>>>(zh_b, wh_b, Wws, part);
  vq_final   <<<8192, 256, 0, stream>>>(part, z, cb, Aws, Wws, out_idx, out_q, wl2, cnt);
  vq_recheckB<<<512, 256, 0, stream>>>(z, cb, Aws, Wws, wl2, cnt, out_idx, out_q);
}